// Round 4
// baseline (658.011 us; speedup 1.0000x reference)
//
#include <hip/hip_runtime.h>
#include <stdint.h>

typedef __bf16 bf16;
typedef bf16 bf16x8 __attribute__((ext_vector_type(8)));
typedef float f32x4 __attribute__((ext_vector_type(4)));
typedef unsigned short u16x8 __attribute__((ext_vector_type(8)));

__device__ __forceinline__ void gload_lds16(const bf16* g, bf16* l) {
    __builtin_amdgcn_global_load_lds(
        (const __attribute__((address_space(1))) void*)g,
        (__attribute__((address_space(3))) void*)l, 16, 0, 0);
}

// ---------------------------------------------------------------------------
// prep_frag: convert w1..w12 fp32 (O,C,10) -> bf16 MFMA A-fragment order:
//   dst[woff + (k32*(O/16) + ot)*512 + lane*8 + j] = W[o=ot*16+(lane&15)]
//        [r = k32*32 + (lane>>4)*8 + j]   with r = k*C + c.
// Block = (layer, ot, 64-c chunk): reads 16 contiguous 2560B runs (coalesced,
// each float exactly once), LDS transpose, writes 20 contiguous 1KB tiles.
// ---------------------------------------------------------------------------
struct PrepArgs {
    const float* src[12];
    int base[12];
    int dstoff[12];
    int Clog[12];
    int OT[12];
    int nClog[12];
};

__global__ __launch_bounds__(256) void prep_frag(PrepArgs a, bf16* __restrict__ dst)
{
    __shared__ bf16 lds[16 * 648];       // 16 o-rows x 640 (c_local*10+k), pad 8
    int bid = blockIdx.x;
    int l = 0;
#pragma unroll
    for (int i = 1; i < 12; i++) if (bid >= a.base[i]) l = i;
    int local = bid - a.base[l];
    int nClog = a.nClog[l];
    int cchunk = local & ((1 << nClog) - 1);
    int ot = local >> nClog;
    int Clog = a.Clog[l];
    int CK10 = 10 << Clog;
    const float* src = a.src[l];
    int t = threadIdx.x;

    size_t sbase = (size_t)(ot * 16) * CK10 + (size_t)cchunk * 640;
#pragma unroll
    for (int it = 0; it < 10; it++) {
        int idx = t + it * 256;          // < 2560
        int m = idx / 160;
        int i4 = idx - m * 160;
        float4 v = *(const float4*)(src + sbase + (size_t)m * CK10 + i4 * 4);
        bf16 b4[4] = {(bf16)v.x, (bf16)v.y, (bf16)v.z, (bf16)v.w};
        *(ushort4*)(&lds[m * 648 + i4 * 4]) = *(ushort4*)b4;
    }
    __syncthreads();

    int sub = t >> 6, ll = t & 63;
    int m = ll & 15, q = ll >> 4;
    int OTl = a.OT[l];
    size_t dbase = (size_t)a.dstoff[l];
#pragma unroll
    for (int tt = 0; tt < 5; tt++) {
        int tile = sub + tt * 4;         // 0..19 -> (k, half)
        int k = tile >> 1, half = tile & 1;
        int k32 = (k << (Clog - 5)) + cchunk * 2 + half;
        bf16 tmp[8];
#pragma unroll
        for (int j = 0; j < 8; j++)
            tmp[j] = lds[m * 648 + (half * 32 + q * 8 + j) * 10 + k];
        *(bf16x8*)(dst + dbase + ((size_t)(k32 * OTl + ot) << 9) + ll * 8) =
            *(bf16x8*)tmp;
    }
}

// ---------------------------------------------------------------------------
// conv0: C=3, K=10, O=64, fp32 VALU. out: [2][81920][64] bf16
// ---------------------------------------------------------------------------
__global__ __launch_bounds__(256) void conv0_kernel(
    const float* __restrict__ x, const float* __restrict__ w0,
    const float* __restrict__ b0, const int* __restrict__ table,
    bf16* __restrict__ out)
{
    const int N = 81920;
    __shared__ float wls[30][64];
    __shared__ float bls[64];
    int tid = threadIdx.x;
    for (int i = tid; i < 1920; i += 256) {
        int o = i / 30, ck = i - o * 30;
        wls[ck][o] = w0[i];
    }
    if (tid < 64) bls[tid] = b0[tid];
    __syncthreads();

    int p = blockIdx.x * 256 + tid;
    int b = p >= N;
    int n = p - b * N;
    int idx[10];
    const int* trow = table + n * 10;
#pragma unroll
    for (int k = 0; k < 10; k++) idx[k] = trow[k];
    float xv[30];
#pragma unroll
    for (int c = 0; c < 3; c++)
#pragma unroll
        for (int k = 0; k < 10; k++)
            xv[c * 10 + k] = x[(b * 3 + c) * N + idx[k]];

    float acc[64];
#pragma unroll
    for (int o = 0; o < 64; o++) acc[o] = bls[o];
    for (int ck = 0; ck < 30; ck++) {
        float xs = xv[ck];
        const f32x4* wrow = (const f32x4*)(&wls[ck][0]);
#pragma unroll
        for (int o4 = 0; o4 < 16; o4++) {
            f32x4 w4 = wrow[o4];
            acc[o4 * 4 + 0] += xs * w4[0];
            acc[o4 * 4 + 1] += xs * w4[1];
            acc[o4 * 4 + 2] += xs * w4[2];
            acc[o4 * 4 + 3] += xs * w4[3];
        }
    }
    bf16x8 ob[8];
#pragma unroll
    for (int i = 0; i < 8; i++)
#pragma unroll
        for (int e = 0; e < 8; e++)
            ob[i][e] = (bf16)fmaxf(acc[i * 8 + e], 0.0f);
    bf16x8* dst = (bf16x8*)(out + (size_t)p * 64);
#pragma unroll
    for (int i = 0; i < 8; i++) dst[i] = ob[i];
}

// ---------------------------------------------------------------------------
// conv_f: gathered GEMM. X staged in LDS (3-buf async global_load_lds,
// XOR-swizzled, bare s_barrier + vmcnt(4)); W read directly from global in
// MFMA fragment order (coalesced 1KB per-wave loads, L2-resident).
// Block = 2x2 waves; wave tile = (TO*16) x (TP*16). BP = TP*32 positions.
// grid = (P/BP, O/(TO*32), S). S>1: fp32 partial slab[z][p*O+o].
// ---------------------------------------------------------------------------
template<int C, int TO, int TP>
__global__ __launch_bounds__(256) void conv_f(
    const bf16* __restrict__ in, const bf16* __restrict__ wfrag,
    const float* __restrict__ bias, const int* __restrict__ table,
    bf16* __restrict__ out, float* __restrict__ slab,
    int N, int O, int S, int PO)
{
    constexpr int BP = TP * 32;
    constexpr int CH = C / 64;
    constexpr int CHUNKS = CH * 10;
    __shared__ bf16 Xs[3][BP][64];
    __shared__ int rowoff[BP][10];

    const int tid = threadIdx.x;
    const int lane = tid & 63;
    const int wid = tid >> 6;
    const int wo = wid & 1, wp = wid >> 1;
    const int l16 = lane & 15, q = lane >> 4;

    const int p0 = blockIdx.x * BP;
    const int o0 = blockIdx.y * (TO * 32);
    const int z = blockIdx.z;
    const int OT = O >> 4;
    const int stride32 = OT * 512;       // elements per k32 step in wfrag

    for (int j = tid; j < BP * 10; j += 256) {
        int pp = j / 10, k = j - pp * 10;
        int p = p0 + pp;
        int b = p >= N;
        int n = p - b * N;
        rowoff[pp][k] = (b * N + table[n * 10 + k]) * C;
    }
    __syncthreads();

    const int lrow = lane >> 3;
    const int gs = (lane & 7) ^ lrow;    // staged seg for this lane's rows
    int srow[TP];
#pragma unroll
    for (int t = 0; t < TP; t++) srow[t] = wid * (TP * 8) + t * 8 + lrow;

    const bf16* wfp[TO];
#pragma unroll
    for (int to = 0; to < TO; to++)
        wfp[to] = wfrag + (size_t)((o0 >> 4) + wo * TO + to) * 512 + lane * 8;

    const int per = CHUNKS / S;
    const int ck0 = z * per;

    auto stage = [&](int chunk, int b3) {
        int k = chunk / CH;
        int cofs = (chunk & (CH - 1)) * 64;
#pragma unroll
        for (int t = 0; t < TP; t++)
            gload_lds16(in + rowoff[srow[t]][k] + cofs + gs * 8,
                        &Xs[b3][wid * (TP * 8) + t * 8][0]);
    };

    f32x4 acc[TO][TP];
#pragma unroll
    for (int a = 0; a < TO; a++)
#pragma unroll
        for (int c = 0; c < TP; c++) acc[a][c] = (f32x4){0.f, 0.f, 0.f, 0.f};

    stage(ck0, 0);
    stage(ck0 + 1, 1);

    const int browb = wp * (TP * 16);
    const int sx = l16 & 7;

    int bi = 0, bs = 2;
    for (int i = 0; i < per; i++) {
        asm volatile("s_waitcnt vmcnt(4)" ::: "memory");
        __builtin_amdgcn_s_barrier();
        const bf16* xb = &Xs[bi][0][0];
        const int kt = ck0 + i;
#pragma unroll
        for (int ks = 0; ks < 2; ks++) {
            size_t wofs = (size_t)(kt * 2 + ks) * stride32;
            int slot = ((ks * 4 + q) ^ sx) * 8;
            bf16x8 af[TO], bfr[TP];
#pragma unroll
            for (int to = 0; to < TO; to++)
                af[to] = *(const bf16x8*)(wfp[to] + wofs);
#pragma unroll
            for (int tp = 0; tp < TP; tp++)
                bfr[tp] = *(const bf16x8*)(xb + (browb + tp * 16 + l16) * 64 + slot);
#pragma unroll
            for (int to = 0; to < TO; to++)
#pragma unroll
                for (int tp = 0; tp < TP; tp++)
                    acc[to][tp] = __builtin_amdgcn_mfma_f32_16x16x32_bf16(
                        af[to], bfr[tp], acc[to][tp], 0, 0, 0);
        }
        int nx = i + 2 < per ? i + 2 : per - 1;
        stage(ck0 + nx, bs);
        bi = bi == 2 ? 0 : bi + 1;
        bs = bs == 2 ? 0 : bs + 1;
    }

    if (S == 1) {
#pragma unroll
        for (int to = 0; to < TO; ++to) {
            int ob = o0 + wo * (TO * 16) + to * 16 + q * 4;
            f32x4 bv = *(const f32x4*)(bias + ob);
#pragma unroll
            for (int tp = 0; tp < TP; ++tp) {
                int p = p0 + browb + tp * 16 + l16;
                union { ushort4 u4; unsigned short s[4]; } pk;
#pragma unroll
                for (int r = 0; r < 4; r++) {
                    float v = fmaxf(acc[to][tp][r] + bv[r], 0.0f);
                    union { bf16 h; unsigned short u; } cc;
                    cc.h = (bf16)v;
                    pk.s[r] = cc.u;
                }
                *(ushort4*)(out + (size_t)p * O + ob) = pk.u4;
            }
        }
    } else {
        float* sb = slab + (size_t)z * PO;
#pragma unroll
        for (int to = 0; to < TO; ++to) {
            int ob = o0 + wo * (TO * 16) + to * 16 + q * 4;
#pragma unroll
            for (int tp = 0; tp < TP; ++tp) {
                int p = p0 + browb + tp * 16 + l16;
                *(f32x4*)(sb + (size_t)p * O + ob) = acc[to][tp];
            }
        }
    }
}

// reduce S slabs + bias + relu -> bf16
__global__ __launch_bounds__(256) void epi_reduce(
    const float* __restrict__ slab, const float* __restrict__ bias,
    bf16* __restrict__ out, int PO, int Omask, int S)
{
    int t4 = (blockIdx.x * 256 + threadIdx.x) * 4;
    if (t4 >= PO) return;
    f32x4 s = *(const f32x4*)(slab + t4);
    for (int zz = 1; zz < S; zz++)
        s += *(const f32x4*)(slab + (size_t)zz * PO + t4);
    int o = t4 & Omask;
    f32x4 bv = *(const f32x4*)(bias + o);
    union { ushort4 u4; unsigned short e[4]; } pk;
#pragma unroll
    for (int r = 0; r < 4; r++) {
        float v = fmaxf(s[r] + bv[r], 0.0f);
        union { bf16 h; unsigned short u; } cc;
        cc.h = (bf16)v;
        pk.e[r] = cc.u;
    }
    *(ushort4*)((unsigned short*)out + t4) = pk.u4;
}

// ---------------------------------------------------------------------------
// Maxpool (bf16 post-ReLU: unsigned-short compare == float compare)
// ---------------------------------------------------------------------------
__global__ __launch_bounds__(256) void pool_kernel(
    const bf16* __restrict__ in, const int* __restrict__ adj,
    const int* __restrict__ pool, bf16* __restrict__ out,
    int N, int M, int c8shift)
{
    int t = blockIdx.x * 256 + threadIdx.x;
    int total = M << c8shift;
    if (t >= total) return;
    int cc = t & ((1 << c8shift) - 1);
    int j = t >> c8shift;
    int b = blockIdx.y;
    int C = 8 << c8shift;
    int s = pool[j];
    const int* a = adj + s * 4;
    const unsigned short* inu = (const unsigned short*)in;
    size_t base = (size_t)b * N * C + (size_t)cc * 8;
    u16x8 m = *(const u16x8*)(inu + base + (size_t)a[0] * C);
#pragma unroll
    for (int i = 1; i < 4; i++) {
        u16x8 v = *(const u16x8*)(inu + base + (size_t)a[i] * C);
#pragma unroll
        for (int e = 0; e < 8; e++) m[e] = v[e] > m[e] ? v[e] : m[e];
    }
    *(u16x8*)((unsigned short*)out + ((size_t)b * M + j) * C + (size_t)cc * 8) = m;
}

// Final pool: in [2][320][512] bf16 -> out (2,512,80) fp32
__global__ __launch_bounds__(256) void final_pool(
    const bf16* __restrict__ in, const int* __restrict__ adj,
    const int* __restrict__ pool, float* __restrict__ out)
{
    int t = blockIdx.x * 256 + threadIdx.x;
    if (t >= 81920) return;
    int j = t % 80;
    int rest = t / 80;
    int c = rest & 511;
    int b = rest >> 9;
    int s = pool[j];
    const int* a = adj + s * 4;
    float m = 0.0f;
#pragma unroll
    for (int i = 0; i < 4; i++) {
        float v = (float)in[((size_t)b * 320 + a[i]) * 512 + c];
        m = fmaxf(m, v);
    }
    out[t] = m;
}

// ---------------------------------------------------------------------------
extern "C" void kernel_launch(void* const* d_in, const int* in_sizes, int n_in,
                              void* d_out, int out_size, void* d_ws, size_t ws_size,
                              hipStream_t stream)
{
    const float* x = (const float*)d_in[0];
    const int* convT[5]; const int* adjT[5]; const int* poolT[5];
    for (int l = 0; l < 5; l++) {
        convT[l] = (const int*)d_in[1 + 3 * l];
        adjT[l]  = (const int*)d_in[2 + 3 * l];
        poolT[l] = (const int*)d_in[3 + 3 * l];
    }
    const float* W[13]; const float* Bs[13];
    for (int i = 0; i < 13; i++) {
        W[i]  = (const float*)d_in[16 + 2 * i];
        Bs[i] = (const float*)d_in[17 + 2 * i];
    }

    // ws: [wfrag 32.7MB | A 21MB | B 21MB | slab 21MB]  (~95.6MB)
    bf16* wbf = (bf16*)d_ws;
    bf16* A  = (bf16*)((char*)d_ws + (size_t)16343040 * 2);
    bf16* Bb = A + 10485760;
    float* slab = (float*)((char*)(Bb + 10485760));

    static const int woff[13] = {0, 0, 40960, 122880, 286720, 614400, 1269760,
                                 1925120, 3235840, 5857280, 8478720, 11100160, 13721600};

    PrepArgs pa;
    {
        static const int clog[12]  = {6,6,7,7,8,8,8,9,9,9,9,9};
        static const int otl[12]   = {4,8,8,16,16,16,32,32,32,32,32,32};
        static const int nclog[12] = {0,0,1,1,2,2,2,3,3,3,3,3};
        static const int basev[12] = {0,4,12,28,60,124,188,316,572,828,1084,1340};
        for (int i = 0; i < 12; i++) {
            pa.src[i] = W[i + 1];
            pa.base[i] = basev[i];
            pa.dstoff[i] = woff[i + 1];
            pa.Clog[i] = clog[i];
            pa.OT[i] = otl[i];
            pa.nClog[i] = nclog[i];
        }
    }
    prep_frag<<<dim3(1596), dim3(256), 0, stream>>>(pa, wbf);

    conv0_kernel<<<dim3(640), dim3(256), 0, stream>>>(x, W[0], Bs[0], convT[0], A);

    const int PO2 = 10240 * 256;
    const int PO3 = 2560 * 512;
    const int PO4 = 640 * 512;

    // level 0
    conv_f<64,2,4><<<dim3(1280, 1, 1), dim3(256), 0, stream>>>(A, wbf + woff[1], Bs[1], convT[0], Bb, slab, 81920, 64, 1, 0);
    pool_kernel<<<dim3(640, 2), dim3(256), 0, stream>>>(Bb, adjT[0], poolT[0], A, 81920, 20480, 3);
    // level 1
    conv_f<64,4,4><<<dim3(320, 1, 1), dim3(256), 0, stream>>>(A, wbf + woff[2], Bs[2], convT[1], Bb, slab, 20480, 128, 1, 0);
    conv_f<128,4,4><<<dim3(320, 1, 1), dim3(256), 0, stream>>>(Bb, wbf + woff[3], Bs[3], convT[1], A, slab, 20480, 128, 1, 0);
    pool_kernel<<<dim3(320, 2), dim3(256), 0, stream>>>(A, adjT[1], poolT[1], Bb, 20480, 5120, 4);
    // level 2 (S=2 -> 320 blocks)
    conv_f<128,4,4><<<dim3(80, 2, 2), dim3(256), 0, stream>>>(Bb, wbf + woff[4], Bs[4], convT[2], A, slab, 5120, 256, 2, PO2);
    epi_reduce<<<dim3(PO2 / 1024), dim3(256), 0, stream>>>(slab, Bs[4], A, PO2, 255, 2);
    conv_f<256,4,4><<<dim3(80, 2, 2), dim3(256), 0, stream>>>(A, wbf + woff[5], Bs[5], convT[2], Bb, slab, 5120, 256, 2, PO2);
    epi_reduce<<<dim3(PO2 / 1024), dim3(256), 0, stream>>>(slab, Bs[5], Bb, PO2, 255, 2);
    conv_f<256,4,4><<<dim3(80, 2, 2), dim3(256), 0, stream>>>(Bb, wbf + woff[6], Bs[6], convT[2], A, slab, 5120, 256, 2, PO2);
    epi_reduce<<<dim3(PO2 / 1024), dim3(256), 0, stream>>>(slab, Bs[6], A, PO2, 255, 2);
    pool_kernel<<<dim3(160, 2), dim3(256), 0, stream>>>(A, adjT[2], poolT[2], Bb, 5120, 1280, 5);
    // level 3 (S=4 -> 320 blocks)
    conv_f<256,4,4><<<dim3(20, 4, 4), dim3(256), 0, stream>>>(Bb, wbf + woff[7], Bs[7], convT[3], A, slab, 1280, 512, 4, PO3);
    epi_reduce<<<dim3(PO3 / 1024), dim3(256), 0, stream>>>(slab, Bs[7], A, PO3, 511, 4);
    conv_f<512,4,4><<<dim3(20, 4, 4), dim3(256), 0, stream>>>(A, wbf + woff[8], Bs[8], convT[3], Bb, slab, 1280, 512, 4, PO3);
    epi_reduce<<<dim3(PO3 / 1024), dim3(256), 0, stream>>>(slab, Bs[8], Bb, PO3, 511, 4);
    conv_f<512,4,4><<<dim3(20, 4, 4), dim3(256), 0, stream>>>(Bb, wbf + woff[9], Bs[9], convT[3], A, slab, 1280, 512, 4, PO3);
    epi_reduce<<<dim3(PO3 / 1024), dim3(256), 0, stream>>>(slab, Bs[9], A, PO3, 511, 4);
    pool_kernel<<<dim3(80, 2), dim3(256), 0, stream>>>(A, adjT[3], poolT[3], Bb, 1280, 320, 6);
    // level 4 (S=16 -> 320 blocks)
    conv_f<512,4,4><<<dim3(5, 4, 16), dim3(256), 0, stream>>>(Bb, wbf + woff[10], Bs[10], convT[4], A, slab, 320, 512, 16, PO4);
    epi_reduce<<<dim3(PO4 / 1024), dim3(256), 0, stream>>>(slab, Bs[10], A, PO4, 511, 16);
    conv_f<512,4,4><<<dim3(5, 4, 16), dim3(256), 0, stream>>>(A, wbf + woff[11], Bs[11], convT[4], Bb, slab, 320, 512, 16, PO4);
    epi_reduce<<<dim3(PO4 / 1024), dim3(256), 0, stream>>>(slab, Bs[11], Bb, PO4, 511, 16);
    conv_f<512,4,4><<<dim3(5, 4, 16), dim3(256), 0, stream>>>(Bb, wbf + woff[12], Bs[12], convT[4], A, slab, 320, 512, 16, PO4);
    epi_reduce<<<dim3(PO4 / 1024), dim3(256), 0, stream>>>(slab, Bs[12], A, PO4, 511, 16);

    final_pool<<<dim3(320), dim3(256), 0, stream>>>(A, adjT[4], poolT[4], (float*)d_out);
}

// Round 5
// 642.465 us; speedup vs baseline: 1.0242x; 1.0242x over previous
//
#include <hip/hip_runtime.h>
#include <stdint.h>

typedef __bf16 bf16;
typedef bf16 bf16x8 __attribute__((ext_vector_type(8)));
typedef float f32x4 __attribute__((ext_vector_type(4)));
typedef unsigned short u16x8 __attribute__((ext_vector_type(8)));

__device__ __forceinline__ void gload_lds16(const bf16* g, bf16* l) {
    __builtin_amdgcn_global_load_lds(
        (const __attribute__((address_space(1))) void*)g,
        (__attribute__((address_space(3))) void*)l, 16, 0, 0);
}

// ---------------------------------------------------------------------------
// prep_frag: convert w1..w12 fp32 (O,C,10) -> bf16 MFMA A-fragment order:
//   dst[woff + (k32*(O/16) + ot)*512 + lane*8 + j] = W[o=ot*16+(lane&15)]
//        [r = k32*32 + (lane>>4)*8 + j]   with r = k*C + c.
// ---------------------------------------------------------------------------
struct PrepArgs {
    const float* src[12];
    int base[12];
    int dstoff[12];
    int Clog[12];
    int OT[12];
    int nClog[12];
};

__global__ __launch_bounds__(256) void prep_frag(PrepArgs a, bf16* __restrict__ dst)
{
    __shared__ bf16 lds[16 * 648];
    int bid = blockIdx.x;
    int l = 0;
#pragma unroll
    for (int i = 1; i < 12; i++) if (bid >= a.base[i]) l = i;
    int local = bid - a.base[l];
    int nClog = a.nClog[l];
    int cchunk = local & ((1 << nClog) - 1);
    int ot = local >> nClog;
    int Clog = a.Clog[l];
    int CK10 = 10 << Clog;
    const float* src = a.src[l];
    int t = threadIdx.x;

    size_t sbase = (size_t)(ot * 16) * CK10 + (size_t)cchunk * 640;
#pragma unroll
    for (int it = 0; it < 10; it++) {
        int idx = t + it * 256;
        int m = idx / 160;
        int i4 = idx - m * 160;
        float4 v = *(const float4*)(src + sbase + (size_t)m * CK10 + i4 * 4);
        bf16 b4[4] = {(bf16)v.x, (bf16)v.y, (bf16)v.z, (bf16)v.w};
        *(ushort4*)(&lds[m * 648 + i4 * 4]) = *(ushort4*)b4;
    }
    __syncthreads();

    int sub = t >> 6, ll = t & 63;
    int m = ll & 15, q = ll >> 4;
    int OTl = a.OT[l];
    size_t dbase = (size_t)a.dstoff[l];
#pragma unroll
    for (int tt = 0; tt < 5; tt++) {
        int tile = sub + tt * 4;
        int k = tile >> 1, half = tile & 1;
        int k32 = (k << (Clog - 5)) + cchunk * 2 + half;
        bf16 tmp[8];
#pragma unroll
        for (int j = 0; j < 8; j++)
            tmp[j] = lds[m * 648 + (half * 32 + q * 8 + j) * 10 + k];
        *(bf16x8*)(dst + dbase + ((size_t)(k32 * OTl + ot) << 9) + ll * 8) =
            *(bf16x8*)tmp;
    }
}

// ---------------------------------------------------------------------------
// conv0: C=3, K=10, O=64, fp32 VALU. out: [2][81920][64] bf16
// ---------------------------------------------------------------------------
__global__ __launch_bounds__(256) void conv0_kernel(
    const float* __restrict__ x, const float* __restrict__ w0,
    const float* __restrict__ b0, const int* __restrict__ table,
    bf16* __restrict__ out)
{
    const int N = 81920;
    __shared__ float wls[30][64];
    __shared__ float bls[64];
    int tid = threadIdx.x;
    for (int i = tid; i < 1920; i += 256) {
        int o = i / 30, ck = i - o * 30;
        wls[ck][o] = w0[i];
    }
    if (tid < 64) bls[tid] = b0[tid];
    __syncthreads();

    int p = blockIdx.x * 256 + tid;
    int b = p >= N;
    int n = p - b * N;
    int idx[10];
    const int* trow = table + n * 10;
#pragma unroll
    for (int k = 0; k < 10; k++) idx[k] = trow[k];
    float xv[30];
#pragma unroll
    for (int c = 0; c < 3; c++)
#pragma unroll
        for (int k = 0; k < 10; k++)
            xv[c * 10 + k] = x[(b * 3 + c) * N + idx[k]];

    float acc[64];
#pragma unroll
    for (int o = 0; o < 64; o++) acc[o] = bls[o];
    for (int ck = 0; ck < 30; ck++) {
        float xs = xv[ck];
        const f32x4* wrow = (const f32x4*)(&wls[ck][0]);
#pragma unroll
        for (int o4 = 0; o4 < 16; o4++) {
            f32x4 w4 = wrow[o4];
            acc[o4 * 4 + 0] += xs * w4[0];
            acc[o4 * 4 + 1] += xs * w4[1];
            acc[o4 * 4 + 2] += xs * w4[2];
            acc[o4 * 4 + 3] += xs * w4[3];
        }
    }
    bf16x8 ob[8];
#pragma unroll
    for (int i = 0; i < 8; i++)
#pragma unroll
        for (int e = 0; e < 8; e++)
            ob[i][e] = (bf16)fmaxf(acc[i * 8 + e], 0.0f);
    bf16x8* dst = (bf16x8*)(out + (size_t)p * 64);
#pragma unroll
    for (int i = 0; i < 8; i++) dst[i] = ob[i];
}

// ---------------------------------------------------------------------------
// conv_f: gathered GEMM. X staged in LDS (3-buf async global_load_lds,
// XOR-swizzled, bare s_barrier + vmcnt(2)); W direct from global in MFMA
// fragment order. Block = 2x2 waves; wave tile (TO*16) x (TP*16); BP=TP*32.
// mode: 0 = no remap; 1 = cluster same-position y-partners on one XCD
// (share gathered X in L2); 2 = cluster same-(y,z) x-partners (share W slice).
// Heuristic: XCD = linear_block_id % 8.
// ---------------------------------------------------------------------------
template<int C, int TO, int TP>
__global__ __launch_bounds__(256) void conv_f(
    const bf16* __restrict__ in, const bf16* __restrict__ wfrag,
    const float* __restrict__ bias, const int* __restrict__ table,
    bf16* __restrict__ out, float* __restrict__ slab,
    int N, int O, int S, int PO, int mode)
{
    constexpr int BP = TP * 32;
    constexpr int CH = C / 64;
    constexpr int CHUNKS = CH * 10;
    __shared__ bf16 Xs[3][BP][64];
    __shared__ int rowoff[BP][10];

    int bx = blockIdx.x, by = blockIdx.y, bz = blockIdx.z;
    if (mode) {
        int gx = gridDim.x, gy = gridDim.y;
        long L = (long)bx + (long)gx * ((long)by + (long)gy * bz);
        int r = (int)(L & 7);
        long q = L >> 3;
        if (mode == 1) {          // y-cluster: needs gx*gy%8==0, gx%8==0
            by = (int)(q % gy);
            long t = q / gy;
            int gx8 = gx >> 3;
            bx = r + 8 * (int)(t % gx8);
            bz = (int)(t / gx8);
        } else {                  // x-cluster: needs total%8==0, gy*gz%8==0
            bx = (int)(q % gx);
            int combo = r + 8 * (int)(q / gx);
            by = combo % gy;
            bz = combo / gy;
        }
    }

    const int tid = threadIdx.x;
    const int lane = tid & 63;
    const int wid = tid >> 6;
    const int wo = wid & 1, wp = wid >> 1;
    const int l16 = lane & 15, q = lane >> 4;

    const int p0 = bx * BP;
    const int o0 = by * (TO * 32);
    const int z = bz;
    const int OT = O >> 4;
    const int stride32 = OT * 512;

    for (int j = tid; j < BP * 10; j += 256) {
        int pp = j / 10, k = j - pp * 10;
        int p = p0 + pp;
        int b = p >= N;
        int n = p - b * N;
        rowoff[pp][k] = (b * N + table[n * 10 + k]) * C;
    }
    __syncthreads();

    const int lrow = lane >> 3;
    const int gs = (lane & 7) ^ lrow;
    int srow[TP];
#pragma unroll
    for (int t = 0; t < TP; t++) srow[t] = wid * (TP * 8) + t * 8 + lrow;

    const bf16* wfp[TO];
#pragma unroll
    for (int to = 0; to < TO; to++)
        wfp[to] = wfrag + (size_t)((o0 >> 4) + wo * TO + to) * 512 + lane * 8;

    const int per = CHUNKS / S;
    const int ck0 = z * per;

    auto stage = [&](int chunk, int b3) {
        int k = chunk / CH;
        int cofs = (chunk & (CH - 1)) * 64;
#pragma unroll
        for (int t = 0; t < TP; t++)
            gload_lds16(in + rowoff[srow[t]][k] + cofs + gs * 8,
                        &Xs[b3][wid * (TP * 8) + t * 8][0]);
    };

    f32x4 acc[TO][TP];
#pragma unroll
    for (int a = 0; a < TO; a++)
#pragma unroll
        for (int c = 0; c < TP; c++) acc[a][c] = (f32x4){0.f, 0.f, 0.f, 0.f};

    stage(ck0, 0);
    stage(ck0 + 1, 1);

    const int browb = wp * (TP * 16);
    const int sx = l16 & 7;

    int bi = 0, bs = 2;
    for (int i = 0; i < per; i++) {
        asm volatile("s_waitcnt vmcnt(2)" ::: "memory");
        __builtin_amdgcn_s_barrier();
        const bf16* xb = &Xs[bi][0][0];
        const int kt = ck0 + i;
#pragma unroll
        for (int ks = 0; ks < 2; ks++) {
            size_t wofs = (size_t)(kt * 2 + ks) * stride32;
            int slot = ((ks * 4 + q) ^ sx) * 8;
            bf16x8 af[TO], bfr[TP];
#pragma unroll
            for (int to = 0; to < TO; to++)
                af[to] = *(const bf16x8*)(wfp[to] + wofs);
#pragma unroll
            for (int tp = 0; tp < TP; tp++)
                bfr[tp] = *(const bf16x8*)(xb + (browb + tp * 16 + l16) * 64 + slot);
#pragma unroll
            for (int to = 0; to < TO; to++)
#pragma unroll
                for (int tp = 0; tp < TP; tp++)
                    acc[to][tp] = __builtin_amdgcn_mfma_f32_16x16x32_bf16(
                        af[to], bfr[tp], acc[to][tp], 0, 0, 0);
        }
        int nx = i + 2 < per ? i + 2 : per - 1;
        stage(ck0 + nx, bs);
        bi = bi == 2 ? 0 : bi + 1;
        bs = bs == 2 ? 0 : bs + 1;
    }

    if (S == 1) {
#pragma unroll
        for (int to = 0; to < TO; ++to) {
            int ob = o0 + wo * (TO * 16) + to * 16 + q * 4;
            f32x4 bv = *(const f32x4*)(bias + ob);
#pragma unroll
            for (int tp = 0; tp < TP; ++tp) {
                int p = p0 + browb + tp * 16 + l16;
                union { ushort4 u4; unsigned short s[4]; } pk;
#pragma unroll
                for (int r = 0; r < 4; r++) {
                    float v = fmaxf(acc[to][tp][r] + bv[r], 0.0f);
                    union { bf16 h; unsigned short u; } cc;
                    cc.h = (bf16)v;
                    pk.s[r] = cc.u;
                }
                *(ushort4*)(out + (size_t)p * O + ob) = pk.u4;
            }
        }
    } else {
        float* sb = slab + (size_t)z * PO;
#pragma unroll
        for (int to = 0; to < TO; ++to) {
            int ob = o0 + wo * (TO * 16) + to * 16 + q * 4;
#pragma unroll
            for (int tp = 0; tp < TP; ++tp) {
                int p = p0 + browb + tp * 16 + l16;
                *(f32x4*)(sb + (size_t)p * O + ob) = acc[to][tp];
            }
        }
    }
}

// reduce S slabs + bias + relu -> bf16
__global__ __launch_bounds__(256) void epi_reduce(
    const float* __restrict__ slab, const float* __restrict__ bias,
    bf16* __restrict__ out, int PO, int Omask, int S)
{
    int t4 = (blockIdx.x * 256 + threadIdx.x) * 4;
    if (t4 >= PO) return;
    f32x4 s = *(const f32x4*)(slab + t4);
    for (int zz = 1; zz < S; zz++)
        s += *(const f32x4*)(slab + (size_t)zz * PO + t4);
    int o = t4 & Omask;
    f32x4 bv = *(const f32x4*)(bias + o);
    union { ushort4 u4; unsigned short e[4]; } pk;
#pragma unroll
    for (int r = 0; r < 4; r++) {
        float v = fmaxf(s[r] + bv[r], 0.0f);
        union { bf16 h; unsigned short u; } cc;
        cc.h = (bf16)v;
        pk.e[r] = cc.u;
    }
    *(ushort4*)((unsigned short*)out + t4) = pk.u4;
}

// ---------------------------------------------------------------------------
// Maxpool (bf16 post-ReLU: unsigned-short compare == float compare)
// ---------------------------------------------------------------------------
__global__ __launch_bounds__(256) void pool_kernel(
    const bf16* __restrict__ in, const int* __restrict__ adj,
    const int* __restrict__ pool, bf16* __restrict__ out,
    int N, int M, int c8shift)
{
    int t = blockIdx.x * 256 + threadIdx.x;
    int total = M << c8shift;
    if (t >= total) return;
    int cc = t & ((1 << c8shift) - 1);
    int j = t >> c8shift;
    int b = blockIdx.y;
    int C = 8 << c8shift;
    int s = pool[j];
    const int* a = adj + s * 4;
    const unsigned short* inu = (const unsigned short*)in;
    size_t base = (size_t)b * N * C + (size_t)cc * 8;
    u16x8 m = *(const u16x8*)(inu + base + (size_t)a[0] * C);
#pragma unroll
    for (int i = 1; i < 4; i++) {
        u16x8 v = *(const u16x8*)(inu + base + (size_t)a[i] * C);
#pragma unroll
        for (int e = 0; e < 8; e++) m[e] = v[e] > m[e] ? v[e] : m[e];
    }
    *(u16x8*)((unsigned short*)out + ((size_t)b * M + j) * C + (size_t)cc * 8) = m;
}

// Final pool: in [2][320][512] bf16 -> out (2,512,80) fp32
__global__ __launch_bounds__(256) void final_pool(
    const bf16* __restrict__ in, const int* __restrict__ adj,
    const int* __restrict__ pool, float* __restrict__ out)
{
    int t = blockIdx.x * 256 + threadIdx.x;
    if (t >= 81920) return;
    int j = t % 80;
    int rest = t / 80;
    int c = rest & 511;
    int b = rest >> 9;
    int s = pool[j];
    const int* a = adj + s * 4;
    float m = 0.0f;
#pragma unroll
    for (int i = 0; i < 4; i++) {
        float v = (float)in[((size_t)b * 320 + a[i]) * 512 + c];
        m = fmaxf(m, v);
    }
    out[t] = m;
}

// ---------------------------------------------------------------------------
extern "C" void kernel_launch(void* const* d_in, const int* in_sizes, int n_in,
                              void* d_out, int out_size, void* d_ws, size_t ws_size,
                              hipStream_t stream)
{
    const float* x = (const float*)d_in[0];
    const int* convT[5]; const int* adjT[5]; const int* poolT[5];
    for (int l = 0; l < 5; l++) {
        convT[l] = (const int*)d_in[1 + 3 * l];
        adjT[l]  = (const int*)d_in[2 + 3 * l];
        poolT[l] = (const int*)d_in[3 + 3 * l];
    }
    const float* W[13]; const float* Bs[13];
    for (int i = 0; i < 13; i++) {
        W[i]  = (const float*)d_in[16 + 2 * i];
        Bs[i] = (const float*)d_in[17 + 2 * i];
    }

    // ws: [wfrag 32.7MB | A 21MB | B 21MB | slab 21MB]
    bf16* wbf = (bf16*)d_ws;
    bf16* A  = (bf16*)((char*)d_ws + (size_t)16343040 * 2);
    bf16* Bb = A + 10485760;
    float* slab = (float*)((char*)(Bb + 10485760));

    static const int woff[13] = {0, 0, 40960, 122880, 286720, 614400, 1269760,
                                 1925120, 3235840, 5857280, 8478720, 11100160, 13721600};

    PrepArgs pa;
    {
        static const int clog[12]  = {6,6,7,7,8,8,8,9,9,9,9,9};
        static const int otl[12]   = {4,8,8,16,16,16,32,32,32,32,32,32};
        static const int nclog[12] = {0,0,1,1,2,2,2,3,3,3,3,3};
        static const int basev[12] = {0,4,12,28,60,124,188,316,572,828,1084,1340};
        for (int i = 0; i < 12; i++) {
            pa.src[i] = W[i + 1];
            pa.base[i] = basev[i];
            pa.dstoff[i] = woff[i + 1];
            pa.Clog[i] = clog[i];
            pa.OT[i] = otl[i];
            pa.nClog[i] = nclog[i];
        }
    }
    prep_frag<<<dim3(1596), dim3(256), 0, stream>>>(pa, wbf);

    conv0_kernel<<<dim3(640), dim3(256), 0, stream>>>(x, W[0], Bs[0], convT[0], A);

    const int PO3 = 2560 * 512;
    const int PO4 = 640 * 512;

    // level 0: 2560 blocks
    conv_f<64,2,2><<<dim3(2560, 1, 1), dim3(256), 0, stream>>>(A, wbf + woff[1], Bs[1], convT[0], Bb, slab, 81920, 64, 1, 0, 0);
    pool_kernel<<<dim3(640, 2), dim3(256), 0, stream>>>(Bb, adjT[0], poolT[0], A, 81920, 20480, 3);
    // level 1: wide-O tiles (BO=128, gy=1 -> X gathered once), 640 blocks
    conv_f<64,4,2><<<dim3(640, 1, 1), dim3(256), 0, stream>>>(A, wbf + woff[2], Bs[2], convT[1], Bb, slab, 20480, 128, 1, 0, 0);
    conv_f<128,4,2><<<dim3(640, 1, 1), dim3(256), 0, stream>>>(Bb, wbf + woff[3], Bs[3], convT[1], A, slab, 20480, 128, 1, 0, 0);
    pool_kernel<<<dim3(320, 2), dim3(256), 0, stream>>>(A, adjT[1], poolT[1], Bb, 20480, 5120, 4);
    // level 2: S=1, 640 blocks, y-cluster for X L2 sharing
    conv_f<128,2,2><<<dim3(160, 4, 1), dim3(256), 0, stream>>>(Bb, wbf + woff[4], Bs[4], convT[2], A, slab, 5120, 256, 1, 0, 1);
    conv_f<256,2,2><<<dim3(160, 4, 1), dim3(256), 0, stream>>>(A, wbf + woff[5], Bs[5], convT[2], Bb, slab, 5120, 256, 1, 0, 1);
    conv_f<256,2,2><<<dim3(160, 4, 1), dim3(256), 0, stream>>>(Bb, wbf + woff[6], Bs[6], convT[2], A, slab, 5120, 256, 1, 0, 1);
    pool_kernel<<<dim3(160, 2), dim3(256), 0, stream>>>(A, adjT[2], poolT[2], Bb, 5120, 1280, 5);
    // level 3: S=2 -> 640 blocks, x-cluster for W slice sharing
    conv_f<256,2,2><<<dim3(40, 8, 2), dim3(256), 0, stream>>>(Bb, wbf + woff[7], Bs[7], convT[3], nullptr, slab, 1280, 512, 2, PO3, 2);
    epi_reduce<<<dim3(PO3 / 1024), dim3(256), 0, stream>>>(slab, Bs[7], A, PO3, 511, 2);
    conv_f<512,2,2><<<dim3(40, 8, 2), dim3(256), 0, stream>>>(A, wbf + woff[8], Bs[8], convT[3], nullptr, slab, 1280, 512, 2, PO3, 2);
    epi_reduce<<<dim3(PO3 / 1024), dim3(256), 0, stream>>>(slab, Bs[8], Bb, PO3, 511, 2);
    conv_f<512,2,2><<<dim3(40, 8, 2), dim3(256), 0, stream>>>(Bb, wbf + woff[9], Bs[9], convT[3], nullptr, slab, 1280, 512, 2, PO3, 2);
    epi_reduce<<<dim3(PO3 / 1024), dim3(256), 0, stream>>>(slab, Bs[9], A, PO3, 511, 2);
    pool_kernel<<<dim3(80, 2), dim3(256), 0, stream>>>(A, adjT[3], poolT[3], Bb, 1280, 320, 6);
    // level 4: S=8 -> 640 blocks, x-cluster
    conv_f<512,2,2><<<dim3(10, 8, 8), dim3(256), 0, stream>>>(Bb, wbf + woff[10], Bs[10], convT[4], nullptr, slab, 320, 512, 8, PO4, 2);
    epi_reduce<<<dim3(PO4 / 1024), dim3(256), 0, stream>>>(slab, Bs[10], A, PO4, 511, 8);
    conv_f<512,2,2><<<dim3(10, 8, 8), dim3(256), 0, stream>>>(A, wbf + woff[11], Bs[11], convT[4], nullptr, slab, 320, 512, 8, PO4, 2);
    epi_reduce<<<dim3(PO4 / 1024), dim3(256), 0, stream>>>(slab, Bs[11], Bb, PO4, 511, 8);
    conv_f<512,2,2><<<dim3(10, 8, 8), dim3(256), 0, stream>>>(Bb, wbf + woff[12], Bs[12], convT[4], nullptr, slab, 320, 512, 8, PO4, 2);
    epi_reduce<<<dim3(PO4 / 1024), dim3(256), 0, stream>>>(slab, Bs[12], A, PO4, 511, 8);

    final_pool<<<dim3(320), dim3(256), 0, stream>>>(A, adjT[4], poolT[4], (float*)d_out);
}

// Round 6
// 598.809 us; speedup vs baseline: 1.0989x; 1.0729x over previous
//
#include <hip/hip_runtime.h>
#include <stdint.h>

typedef __bf16 bf16;
typedef bf16 bf16x8 __attribute__((ext_vector_type(8)));
typedef float f32x4 __attribute__((ext_vector_type(4)));
typedef unsigned short u16x8 __attribute__((ext_vector_type(8)));

__device__ __forceinline__ void gload_lds16(const bf16* g, bf16* l) {
    __builtin_amdgcn_global_load_lds(
        (const __attribute__((address_space(1))) void*)g,
        (__attribute__((address_space(3))) void*)l, 16, 0, 0);
}

// ---------------------------------------------------------------------------
// prep_frag: convert w1..w12 fp32 (O,C,10) -> bf16 MFMA A-fragment order:
//   dst[woff + (k32*(O/16) + ot)*512 + lane*8 + j] = W[o=ot*16+(lane&15)]
//        [r = k32*32 + (lane>>4)*8 + j]   with r = k*C + c.
// ---------------------------------------------------------------------------
struct PrepArgs {
    const float* src[12];
    int base[12];
    int dstoff[12];
    int Clog[12];
    int OT[12];
    int nClog[12];
};

__global__ __launch_bounds__(256) void prep_frag(PrepArgs a, bf16* __restrict__ dst)
{
    __shared__ bf16 lds[16 * 648];
    int bid = blockIdx.x;
    int l = 0;
#pragma unroll
    for (int i = 1; i < 12; i++) if (bid >= a.base[i]) l = i;
    int local = bid - a.base[l];
    int nClog = a.nClog[l];
    int cchunk = local & ((1 << nClog) - 1);
    int ot = local >> nClog;
    int Clog = a.Clog[l];
    int CK10 = 10 << Clog;
    const float* src = a.src[l];
    int t = threadIdx.x;

    size_t sbase = (size_t)(ot * 16) * CK10 + (size_t)cchunk * 640;
#pragma unroll
    for (int it = 0; it < 10; it++) {
        int idx = t + it * 256;
        int m = idx / 160;
        int i4 = idx - m * 160;
        float4 v = *(const float4*)(src + sbase + (size_t)m * CK10 + i4 * 4);
        bf16 b4[4] = {(bf16)v.x, (bf16)v.y, (bf16)v.z, (bf16)v.w};
        *(ushort4*)(&lds[m * 648 + i4 * 4]) = *(ushort4*)b4;
    }
    __syncthreads();

    int sub = t >> 6, ll = t & 63;
    int m = ll & 15, q = ll >> 4;
    int OTl = a.OT[l];
    size_t dbase = (size_t)a.dstoff[l];
#pragma unroll
    for (int tt = 0; tt < 5; tt++) {
        int tile = sub + tt * 4;
        int k = tile >> 1, half = tile & 1;
        int k32 = (k << (Clog - 5)) + cchunk * 2 + half;
        bf16 tmp[8];
#pragma unroll
        for (int j = 0; j < 8; j++)
            tmp[j] = lds[m * 648 + (half * 32 + q * 8 + j) * 10 + k];
        *(bf16x8*)(dst + dbase + ((size_t)(k32 * OTl + ot) << 9) + ll * 8) =
            *(bf16x8*)tmp;
    }
}

// ---------------------------------------------------------------------------
// conv0: C=3, K=10, O=64, fp32 VALU. out: [2][81920][64] bf16
// ---------------------------------------------------------------------------
__global__ __launch_bounds__(256) void conv0_kernel(
    const float* __restrict__ x, const float* __restrict__ w0,
    const float* __restrict__ b0, const int* __restrict__ table,
    bf16* __restrict__ out)
{
    const int N = 81920;
    __shared__ float wls[30][64];
    __shared__ float bls[64];
    int tid = threadIdx.x;
    for (int i = tid; i < 1920; i += 256) {
        int o = i / 30, ck = i - o * 30;
        wls[ck][o] = w0[i];
    }
    if (tid < 64) bls[tid] = b0[tid];
    __syncthreads();

    int p = blockIdx.x * 256 + tid;
    int b = p >= N;
    int n = p - b * N;
    int idx[10];
    const int* trow = table + n * 10;
#pragma unroll
    for (int k = 0; k < 10; k++) idx[k] = trow[k];
    float xv[30];
#pragma unroll
    for (int c = 0; c < 3; c++)
#pragma unroll
        for (int k = 0; k < 10; k++)
            xv[c * 10 + k] = x[(b * 3 + c) * N + idx[k]];

    float acc[64];
#pragma unroll
    for (int o = 0; o < 64; o++) acc[o] = bls[o];
    for (int ck = 0; ck < 30; ck++) {
        float xs = xv[ck];
        const f32x4* wrow = (const f32x4*)(&wls[ck][0]);
#pragma unroll
        for (int o4 = 0; o4 < 16; o4++) {
            f32x4 w4 = wrow[o4];
            acc[o4 * 4 + 0] += xs * w4[0];
            acc[o4 * 4 + 1] += xs * w4[1];
            acc[o4 * 4 + 2] += xs * w4[2];
            acc[o4 * 4 + 3] += xs * w4[3];
        }
    }
    bf16x8 ob[8];
#pragma unroll
    for (int i = 0; i < 8; i++)
#pragma unroll
        for (int e = 0; e < 8; e++)
            ob[i][e] = (bf16)fmaxf(acc[i * 8 + e], 0.0f);
    bf16x8* dst = (bf16x8*)(out + (size_t)p * 64);
#pragma unroll
    for (int i = 0; i < 8; i++) dst[i] = ob[i];
}

// ---------------------------------------------------------------------------
// conv_f: gathered GEMM, deep async pipeline.
//  - X: 3-buffer LDS via global_load_lds, prefetch distance 2.
//  - W: per-wave register double-buffer from fragment-ordered global (L2).
//  - __builtin_amdgcn_s_waitcnt (NOT inline asm -> no hidden vmcnt(0) drain)
//    + bare s_barrier + sched_barrier(0) pins. vmcnt completes in order:
//    waiting to depth 2*TO+TP exactly drains the 2-chunks-old X stage.
// Block = 2x2 waves; wave tile (TO*16)x(TP*16); BP=TP*32, BO=TO*32.
// grid = (P/BP, O/BO, S). S>1: fp32 partial slab (nontemporal stores).
// ---------------------------------------------------------------------------
template<int C, int TO, int TP>
__global__ __launch_bounds__(256) void conv_f(
    const bf16* __restrict__ in, const bf16* __restrict__ wfrag,
    const float* __restrict__ bias, const int* __restrict__ table,
    bf16* __restrict__ out, float* __restrict__ slab,
    int N, int O, int S, int PO)
{
    constexpr int BP = TP * 32;
    constexpr int CH = C / 64;           // 64-ch chunks per k (pow2)
    constexpr int CHUNKS = CH * 10;
    constexpr int NW = 2 * TO + TP;      // vmcnt depth to keep
    constexpr int IMM = NW | 0x70 | 0xF00;
    __shared__ bf16 Xs[3][BP][64];
    __shared__ int rowoff[BP][10];

    const int tid = threadIdx.x;
    const int lane = tid & 63;
    const int wid = tid >> 6;
    const int wo = wid & 1, wp = wid >> 1;
    const int l16 = lane & 15, q = lane >> 4;

    const int p0 = blockIdx.x * BP;
    const int o0 = blockIdx.y * (TO * 32);
    const int z = blockIdx.z;
    const int OT = O >> 4;

    for (int j = tid; j < BP * 10; j += 256) {
        int pp = j / 10, k = j - pp * 10;
        int p = p0 + pp;
        int b = p >= N;
        int n = p - b * N;
        rowoff[pp][k] = (b * N + table[n * 10 + k]) * C;
    }
    __syncthreads();

    const int lrow = lane >> 3;
    const int gs = (lane & 7) ^ lrow;
    int srow[TP];
#pragma unroll
    for (int t = 0; t < TP; t++) srow[t] = wid * (TP * 8) + t * 8 + lrow;

    const int obase = (o0 >> 4) + wo * TO;

    const int per = CHUNKS / S;          // even (>=10) for all instantiations
    const int ck0 = z * per;

    auto stage = [&](int chunk, int b3) {
        int k = chunk / CH;
        int cofs = (chunk & (CH - 1)) * 64;
#pragma unroll
        for (int t = 0; t < TP; t++)
            gload_lds16(in + rowoff[srow[t]][k] + cofs + gs * 8,
                        &Xs[b3][wid * (TP * 8) + t * 8][0]);
    };
    auto loadW = [&](int chunk, bf16x8* dstA) {
        int k32b = chunk * 2;
#pragma unroll
        for (int ks = 0; ks < 2; ks++)
#pragma unroll
            for (int to = 0; to < TO; to++)
                dstA[ks * TO + to] = *(const bf16x8*)(
                    wfrag + (((size_t)(k32b + ks) * OT + obase + to) << 9) + lane * 8);
    };

    f32x4 acc[TO][TP];
#pragma unroll
    for (int a = 0; a < TO; a++)
#pragma unroll
        for (int c = 0; c < TP; c++) acc[a][c] = (f32x4){0.f, 0.f, 0.f, 0.f};

    bf16x8 wrA[2 * TO], wrB[2 * TO];

    // prologue: order = stage(0), loadW(0), stage(1)  -> after stage(0) there
    // are exactly NW newer vmem ops, matching the steady-state wait depth.
    stage(ck0, 0);
    loadW(ck0, wrA);
    stage(ck0 + 1, 1);

    const int browb = wp * (TP * 16);
    const int sx = l16 & 7;

    auto iter = [&](int j, bf16x8* cur, bf16x8* nxt, int bi, int bs) {
        __builtin_amdgcn_s_waitcnt(IMM);      // drain stage(j) (in-order vmcnt)
        __builtin_amdgcn_s_barrier();         // all waves' stage(j) complete
        __builtin_amdgcn_sched_barrier(0);
        int wc = j + 1 < per ? j + 1 : per - 1;
        loadW(ck0 + wc, nxt);
        int xc = j + 2 < per ? j + 2 : per - 1;
        stage(ck0 + xc, bs);
        __builtin_amdgcn_sched_barrier(0);
        const bf16* xb = &Xs[bi][0][0];
#pragma unroll
        for (int ks = 0; ks < 2; ks++) {
            int slot = ((ks * 4 + q) ^ sx) * 8;
            bf16x8 bfr[TP];
#pragma unroll
            for (int tp = 0; tp < TP; tp++)
                bfr[tp] = *(const bf16x8*)(xb + (browb + tp * 16 + l16) * 64 + slot);
#pragma unroll
            for (int to = 0; to < TO; to++)
#pragma unroll
                for (int tp = 0; tp < TP; tp++)
                    acc[to][tp] = __builtin_amdgcn_mfma_f32_16x16x32_bf16(
                        cur[ks * TO + to], bfr[tp], acc[to][tp], 0, 0, 0);
        }
    };

    int bi = 0, bs = 2;
    for (int j = 0; j < per; j += 2) {
        iter(j, wrA, wrB, bi, bs);
        bi = bi == 2 ? 0 : bi + 1; bs = bs == 2 ? 0 : bs + 1;
        iter(j + 1, wrB, wrA, bi, bs);
        bi = bi == 2 ? 0 : bi + 1; bs = bs == 2 ? 0 : bs + 1;
    }

    if (S == 1) {
#pragma unroll
        for (int to = 0; to < TO; ++to) {
            int ob = o0 + wo * (TO * 16) + to * 16 + q * 4;
            f32x4 bv = *(const f32x4*)(bias + ob);
#pragma unroll
            for (int tp = 0; tp < TP; ++tp) {
                int p = p0 + browb + tp * 16 + l16;
                union { ushort4 u4; unsigned short s[4]; } pk;
#pragma unroll
                for (int r = 0; r < 4; r++) {
                    float v = fmaxf(acc[to][tp][r] + bv[r], 0.0f);
                    union { bf16 h; unsigned short u; } cc;
                    cc.h = (bf16)v;
                    pk.s[r] = cc.u;
                }
                *(ushort4*)(out + (size_t)p * O + ob) = pk.u4;
            }
        }
    } else {
        float* sb = slab + (size_t)z * PO;
#pragma unroll
        for (int to = 0; to < TO; ++to) {
            int ob = o0 + wo * (TO * 16) + to * 16 + q * 4;
#pragma unroll
            for (int tp = 0; tp < TP; ++tp) {
                int p = p0 + browb + tp * 16 + l16;
                __builtin_nontemporal_store(acc[to][tp],
                    (f32x4*)(sb + (size_t)p * O + ob));
            }
        }
    }
}

// reduce S slabs + bias + relu -> bf16 (nontemporal slab reads)
__global__ __launch_bounds__(256) void epi_reduce(
    const float* __restrict__ slab, const float* __restrict__ bias,
    bf16* __restrict__ out, int PO, int Omask, int S)
{
    int t4 = (blockIdx.x * 256 + threadIdx.x) * 4;
    if (t4 >= PO) return;
    f32x4 s = __builtin_nontemporal_load((const f32x4*)(slab + t4));
    for (int zz = 1; zz < S; zz++)
        s += __builtin_nontemporal_load((const f32x4*)(slab + (size_t)zz * PO + t4));
    int o = t4 & Omask;
    f32x4 bv = *(const f32x4*)(bias + o);
    union { ushort4 u4; unsigned short e[4]; } pk;
#pragma unroll
    for (int r = 0; r < 4; r++) {
        float v = fmaxf(s[r] + bv[r], 0.0f);
        union { bf16 h; unsigned short u; } cc;
        cc.h = (bf16)v;
        pk.e[r] = cc.u;
    }
    *(ushort4*)((unsigned short*)out + t4) = pk.u4;
}

// ---------------------------------------------------------------------------
// Maxpool (bf16 post-ReLU: unsigned-short compare == float compare)
// ---------------------------------------------------------------------------
__global__ __launch_bounds__(256) void pool_kernel(
    const bf16* __restrict__ in, const int* __restrict__ adj,
    const int* __restrict__ pool, bf16* __restrict__ out,
    int N, int M, int c8shift)
{
    int t = blockIdx.x * 256 + threadIdx.x;
    int total = M << c8shift;
    if (t >= total) return;
    int cc = t & ((1 << c8shift) - 1);
    int j = t >> c8shift;
    int b = blockIdx.y;
    int C = 8 << c8shift;
    int s = pool[j];
    const int* a = adj + s * 4;
    const unsigned short* inu = (const unsigned short*)in;
    size_t base = (size_t)b * N * C + (size_t)cc * 8;
    u16x8 m = *(const u16x8*)(inu + base + (size_t)a[0] * C);
#pragma unroll
    for (int i = 1; i < 4; i++) {
        u16x8 v = *(const u16x8*)(inu + base + (size_t)a[i] * C);
#pragma unroll
        for (int e = 0; e < 8; e++) m[e] = v[e] > m[e] ? v[e] : m[e];
    }
    *(u16x8*)((unsigned short*)out + ((size_t)b * M + j) * C + (size_t)cc * 8) = m;
}

// Final pool: in [2][320][512] bf16 -> out (2,512,80) fp32
__global__ __launch_bounds__(256) void final_pool(
    const bf16* __restrict__ in, const int* __restrict__ adj,
    const int* __restrict__ pool, float* __restrict__ out)
{
    int t = blockIdx.x * 256 + threadIdx.x;
    if (t >= 81920) return;
    int j = t % 80;
    int rest = t / 80;
    int c = rest & 511;
    int b = rest >> 9;
    int s = pool[j];
    const int* a = adj + s * 4;
    float m = 0.0f;
#pragma unroll
    for (int i = 0; i < 4; i++) {
        float v = (float)in[((size_t)b * 320 + a[i]) * 512 + c];
        m = fmaxf(m, v);
    }
    out[t] = m;
}

// ---------------------------------------------------------------------------
extern "C" void kernel_launch(void* const* d_in, const int* in_sizes, int n_in,
                              void* d_out, int out_size, void* d_ws, size_t ws_size,
                              hipStream_t stream)
{
    const float* x = (const float*)d_in[0];
    const int* convT[5]; const int* adjT[5]; const int* poolT[5];
    for (int l = 0; l < 5; l++) {
        convT[l] = (const int*)d_in[1 + 3 * l];
        adjT[l]  = (const int*)d_in[2 + 3 * l];
        poolT[l] = (const int*)d_in[3 + 3 * l];
    }
    const float* W[13]; const float* Bs[13];
    for (int i = 0; i < 13; i++) {
        W[i]  = (const float*)d_in[16 + 2 * i];
        Bs[i] = (const float*)d_in[17 + 2 * i];
    }

    // ws: [wfrag 32.7MB | A 21MB | B 21MB | slab 21MB]
    bf16* wbf = (bf16*)d_ws;
    bf16* A  = (bf16*)((char*)d_ws + (size_t)16343040 * 2);
    bf16* Bb = A + 10485760;
    float* slab = (float*)((char*)(Bb + 10485760));

    static const int woff[13] = {0, 0, 40960, 122880, 286720, 614400, 1269760,
                                 1925120, 3235840, 5857280, 8478720, 11100160, 13721600};

    PrepArgs pa;
    {
        static const int clog[12]  = {6,6,7,7,8,8,8,9,9,9,9,9};
        static const int otl[12]   = {4,8,8,16,16,16,32,32,32,32,32,32};
        static const int nclog[12] = {0,0,1,1,2,2,2,3,3,3,3,3};
        static const int basev[12] = {0,4,12,28,60,124,188,316,572,828,1084,1340};
        for (int i = 0; i < 12; i++) {
            pa.src[i] = W[i + 1];
            pa.base[i] = basev[i];
            pa.dstoff[i] = woff[i + 1];
            pa.Clog[i] = clog[i];
            pa.OT[i] = otl[i];
            pa.nClog[i] = nclog[i];
        }
    }
    prep_frag<<<dim3(1596), dim3(256), 0, stream>>>(pa, wbf);

    conv0_kernel<<<dim3(640), dim3(256), 0, stream>>>(x, W[0], Bs[0], convT[0], A);

    const int PO2 = 10240 * 256;
    const int PO3 = 2560 * 512;
    const int PO4 = 640 * 512;

    // level 0: O=64 -> BO=64 (TO=2), BP=128, 1280 blocks
    conv_f<64,2,4><<<dim3(1280, 1, 1), dim3(256), 0, stream>>>(A, wbf + woff[1], Bs[1], convT[0], Bb, slab, 81920, 64, 1, 0);
    pool_kernel<<<dim3(640, 2), dim3(256), 0, stream>>>(Bb, adjT[0], poolT[0], A, 81920, 20480, 3);
    // level 1: 128x128 tiles, 320 blocks
    conv_f<64,4,4><<<dim3(320, 1, 1), dim3(256), 0, stream>>>(A, wbf + woff[2], Bs[2], convT[1], Bb, slab, 20480, 128, 1, 0);
    conv_f<128,4,4><<<dim3(320, 1, 1), dim3(256), 0, stream>>>(Bb, wbf + woff[3], Bs[3], convT[1], A, slab, 20480, 128, 1, 0);
    pool_kernel<<<dim3(320, 2), dim3(256), 0, stream>>>(A, adjT[1], poolT[1], Bb, 20480, 5120, 4);
    // level 2: 128x128, S=2 -> 320 blocks
    conv_f<128,4,4><<<dim3(80, 2, 2), dim3(256), 0, stream>>>(Bb, wbf + woff[4], Bs[4], convT[2], A, slab, 5120, 256, 2, PO2);
    epi_reduce<<<dim3(PO2 / 1024), dim3(256), 0, stream>>>(slab, Bs[4], A, PO2, 255, 2);
    conv_f<256,4,4><<<dim3(80, 2, 2), dim3(256), 0, stream>>>(A, wbf + woff[5], Bs[5], convT[2], Bb, slab, 5120, 256, 2, PO2);
    epi_reduce<<<dim3(PO2 / 1024), dim3(256), 0, stream>>>(slab, Bs[5], Bb, PO2, 255, 2);
    conv_f<256,4,4><<<dim3(80, 2, 2), dim3(256), 0, stream>>>(Bb, wbf + woff[6], Bs[6], convT[2], A, slab, 5120, 256, 2, PO2);
    epi_reduce<<<dim3(PO2 / 1024), dim3(256), 0, stream>>>(slab, Bs[6], A, PO2, 255, 2);
    pool_kernel<<<dim3(160, 2), dim3(256), 0, stream>>>(A, adjT[2], poolT[2], Bb, 5120, 1280, 5);
    // level 3: 128x128, S=4 -> 320 blocks
    conv_f<256,4,4><<<dim3(20, 4, 4), dim3(256), 0, stream>>>(Bb, wbf + woff[7], Bs[7], convT[3], A, slab, 1280, 512, 4, PO3);
    epi_reduce<<<dim3(PO3 / 1024), dim3(256), 0, stream>>>(slab, Bs[7], A, PO3, 511, 4);
    conv_f<512,4,4><<<dim3(20, 4, 4), dim3(256), 0, stream>>>(A, wbf + woff[8], Bs[8], convT[3], Bb, slab, 1280, 512, 4, PO3);
    epi_reduce<<<dim3(PO3 / 1024), dim3(256), 0, stream>>>(slab, Bs[8], Bb, PO3, 511, 4);
    conv_f<512,4,4><<<dim3(20, 4, 4), dim3(256), 0, stream>>>(Bb, wbf + woff[9], Bs[9], convT[3], A, slab, 1280, 512, 4, PO3);
    epi_reduce<<<dim3(PO3 / 1024), dim3(256), 0, stream>>>(slab, Bs[9], A, PO3, 511, 4);
    pool_kernel<<<dim3(80, 2), dim3(256), 0, stream>>>(A, adjT[3], poolT[3], Bb, 1280, 320, 6);
    // level 4: 64x128 (TO=2), S=8 -> 320 blocks
    conv_f<512,2,4><<<dim3(5, 8, 8), dim3(256), 0, stream>>>(Bb, wbf + woff[10], Bs[10], convT[4], A, slab, 320, 512, 8, PO4);
    epi_reduce<<<dim3(PO4 / 1024), dim3(256), 0, stream>>>(slab, Bs[10], A, PO4, 511, 8);
    conv_f<512,2,4><<<dim3(5, 8, 8), dim3(256), 0, stream>>>(A, wbf + woff[11], Bs[11], convT[4], Bb, slab, 320, 512, 8, PO4);
    epi_reduce<<<dim3(PO4 / 1024), dim3(256), 0, stream>>>(slab, Bs[11], Bb, PO4, 511, 8);
    conv_f<512,2,4><<<dim3(5, 8, 8), dim3(256), 0, stream>>>(Bb, wbf + woff[12], Bs[12], convT[4], A, slab, 320, 512, 8, PO4);
    epi_reduce<<<dim3(PO4 / 1024), dim3(256), 0, stream>>>(slab, Bs[12], A, PO4, 511, 8);

    final_pool<<<dim3(320), dim3(256), 0, stream>>>(A, adjT[4], poolT[4], (float*)d_out);
}